// Round 18
// baseline (42.572 us; speedup 1.0000x reference)
//
#include <hip/hip_runtime.h>
#include <hip/hip_fp16.h>
#include <math.h>

#define PATCH 41
#define PSIZE (PATCH * PATCH)   // 1681
#define NUM_ANG 8
#define KS 16
#define STRIDE 10
#define PAD 4
#define DESC 128
#define CLIPVAL 0.2f

#define NQ4 (PATCH * 10)         // 410 uniform quads (x = 0..39)
#define CST 33                   // colsum row stride (floats, ODD)
#define PIXSTRIDE 43             // slot row stride in pixels: 43 mod 8 = 3 -> bank spread
#define ROWH (PIXSTRIDE * 8)     // 344 halves per row

struct F4 { float x, y, z, w; };

typedef float    f2v __attribute__((ext_vector_type(2)));
typedef _Float16 h2t __attribute__((ext_vector_type(2)));

// ---- DPP-based wave64 sum (VALU pipe only, no LDS, no barriers) ----
template <int CTRL>
__device__ __forceinline__ float dpp_add(float v) {
    const int s = __builtin_amdgcn_update_dpp(
        0, __builtin_bit_cast(int, v), CTRL, 0xF, 0xF, true);
    return v + __builtin_bit_cast(float, s);
}
__device__ __forceinline__ float wave_sum_dpp(float v) {
    v = dpp_add<0x111>(v);   // row_shr:1
    v = dpp_add<0x112>(v);   // row_shr:2
    v = dpp_add<0x114>(v);   // row_shr:4
    v = dpp_add<0x118>(v);   // row_shr:8
    v = dpp_add<0x142>(v);   // row_bcast:15
    v = dpp_add<0x143>(v);   // row_bcast:31 -> lane 63 = total
    return __builtin_bit_cast(float,
        __builtin_amdgcn_readlane(__builtin_bit_cast(int, v), 63));
}

// per-pixel: UN-HALVED gradients -> orientation -> FULL 8-half slot, ONE b128 write
__device__ __forceinline__ void bin_px(__half* slotp, float gx2, float gy2, float gkv) {
    float g2 = fmaf(gx2, gx2, 4e-10f);
    g2 = fmaf(gy2, gy2, g2);
    const float mag = __builtin_amdgcn_sqrtf(g2) * (gkv * 512.0f);

    const float gxp = gx2 + 2e-10f;
    const float ax = fabsf(gxp), ay = fabsf(gy2);
    const float mx = fmaxf(ax, ay);
    const float mn = fminf(ax, ay);
    const float t  = mn * __builtin_amdgcn_rcpf(fmaxf(mx, 1e-20f));
    const float s  = t * t;
    float r = t * fmaf(s, fmaf(s, fmaf(s, fmaf(s, 0.02652810f, -0.10839420f),
                                       0.22936229f), -0.42055650f), 1.27306897f);
    r = (ay > ax)     ? 2.0f - r : r;
    r = (gxp < 0.0f)  ? 4.0f - r : r;
    r = (gy2 < 0.0f)  ? 8.0f - r : r;      // octant units in [0, 8]

    const float bf = floorf(r);
    const float f  = r - bf;
    const int e  = ((int)bf) & (NUM_ANG - 1);      // b0
    const unsigned int w0h = __half_as_ushort(__float2half((1.0f - f) * mag));
    const unsigned int w1h = __half_as_ushort(__float2half(f * mag));

    // place w0 at half-slot e, w1 at half-slot (e+1)&7, zeros elsewhere
    const int sh = (e & 1) << 4;
    const unsigned int w0s = w0h << sh;
    const unsigned int w1s = w1h << (sh ^ 16);
    const int d0 = e >> 1;
    const int dB = (d0 + 1) & 3;
    const unsigned int vA = (e & 1) ? w0s : (w0s | w1s);
    const unsigned int vB = (e & 1) ? w1s : 0u;

    uint4 slot;
    slot.x = (d0 == 0 ? vA : 0u) | (dB == 0 ? vB : 0u);
    slot.y = (d0 == 1 ? vA : 0u) | (dB == 1 ? vB : 0u);
    slot.z = (d0 == 2 ? vA : 0u) | (dB == 2 ? vB : 0u);
    slot.w = (d0 == 3 ? vA : 0u) | (dB == 3 ? vB : 0u);
    *(uint4*)slotp = slot;
}

__global__ __launch_bounds__(512) void sift_desc_kernel(
    const float* __restrict__ input,
    const float* __restrict__ gk,
    float* __restrict__ out)
{
    __shared__ __align__(16) __half s_bins[PATCH * ROWH];  // 28208 B, [y][43px][8a]
    __shared__ float s_cs[PATCH * CST];                    // 5412 B

    const int tid = threadIdx.x;
    const int b   = blockIdx.x;
    const float* in_p = input + (size_t)b * PSIZE;

    const float w1r[KS] = {0.0625f, 0.1875f, 0.3125f, 0.4375f,
                           0.5625f, 0.6875f, 0.8125f, 0.9375f,
                           0.9375f, 0.8125f, 0.6875f, 0.5625f,
                           0.4375f, 0.3125f, 0.1875f, 0.0625f};

    // ---- phase 1 (flat, no zeroing): one quad/thread; tail col on wave-7 ----
    if (tid < NQ4) {
        const int y  = tid / 10;
        const int xq = (tid - y * 10) * 4;
        const int ym = max(y - 1, 0), yp = min(y + 1, PATCH - 1);
        const float* cr = in_p + y  * PATCH;
        const float* ur = in_p + ym * PATCH;
        const float* dr = in_p + yp * PATCH;
        const float* gr = gk + y * PATCH;
        __half* srow = s_bins + y * ROWH + xq * NUM_ANG;

        const F4 c = *(const F4*)(cr + xq);
        const F4 u = *(const F4*)(ur + xq);
        const F4 d = *(const F4*)(dr + xq);
        const F4 g = *(const F4*)(gr + xq);
        const float L = cr[max(xq - 1, 0)];
        const float R = cr[xq + 4];

        bin_px(srow,      (c.y - L),   (d.x - u.x), g.x);
        bin_px(srow + 8,  (c.z - c.x), (d.y - u.y), g.y);
        bin_px(srow + 16, (c.w - c.y), (d.z - u.z), g.z);
        bin_px(srow + 24, (R  - c.z),  (d.w - u.w), g.w);
    } else if (tid >= 448 && tid < 448 + PATCH) {   // tail column x = 40
        const int y = tid - 448;
        const int ym = max(y - 1, 0), yp = min(y + 1, PATCH - 1);
        const float* cr = in_p + y * PATCH;
        bin_px(s_bins + y * ROWH + 40 * NUM_ANG,
               (cr[40] - cr[39]),
               (in_p[yp * PATCH + 40] - in_p[ym * PATCH + 40]),
               gk[y * PATCH + 40]);
    }
    __syncthreads();

    // ---- phase 2a: thread = (angle-pair k, row y); 41 b32 reads, pk_fma accum ----
    if (tid < PATCH * 4) {
        const int k = tid & 3;        // angle pair: angles 2k, 2k+1
        const int y = tid >> 2;
        const __half* sb = s_bins + y * ROWH + k * 2;

        f2v acc[4];
        #pragma unroll
        for (int i = 0; i < 4; ++i) acc[i] = (f2v){0.0f, 0.0f};

        #pragma unroll
        for (int x = 0; x < PATCH; ++x) {
            const h2t h  = *(const h2t*)(sb + x * NUM_ANG);
            const f2v hf = __builtin_convertvector(h, f2v);
            #pragma unroll
            for (int j = 0; j < 4; ++j) {
                const int dd = x - (j * STRIDE - PAD);
                if (dd >= 0 && dd < KS) {           // compile-time after unroll
                    const float w = ((dd < 8 ? dd : 15 - dd) + 0.5f) * 0.125f;
                    acc[j] = __builtin_elementwise_fma((f2v){w, w}, hf, acc[j]);
                }
            }
        }
        float* cs = s_cs + y * CST + k * 2;
        #pragma unroll
        for (int j = 0; j < 4; ++j) {
            cs[j * 8]     = acc[j].x;
            cs[j * 8 + 1] = acc[j].y;
        }
    }
    __syncthreads();

    // ---- phases 2b + norm: single wave, DPP reductions ----
    if (tid < 64) {
        const int lane = tid;
        float v0 = 0.0f, v1 = 0.0f;
        int a0i = 0, jj0 = 0, ii0 = 0, a1i = 0, jj1 = 0, ii1 = 0;
        #pragma unroll
        for (int h = 0; h < 2; ++h) {
            const int item = lane + h * 64;
            const int a  = item & 7;
            const int jj = (item >> 3) & 3;
            const int ii = item >> 5;
            const int py0 = ii * STRIDE - PAD;
            float s = 0.0f;
            #pragma unroll
            for (int dy = 0; dy < KS; ++dy) {
                const int py  = py0 + dy;
                const int pyc = min(max(py, 0), PATCH - 1);
                const float wv = (py == pyc) ? w1r[dy] : 0.0f;
                s = fmaf(wv, s_cs[pyc * CST + jj * 8 + a], s);
            }
            if (h == 0) { v0 = s; a0i = a; jj0 = jj; ii0 = ii; }
            else        { v1 = s; a1i = a; jj1 = jj; ii1 = ii; }
        }

        const float ss1 = wave_sum_dpp(fmaf(v0, v0, v1 * v1));
        const float inv1 = 1.0f / fmaxf(sqrtf(ss1), 1e-12f);
        const float c0 = fminf(fmaxf(v0 * inv1, 0.0f), CLIPVAL);
        const float c1 = fminf(fmaxf(v1 * inv1, 0.0f), CLIPVAL);

        const float ss2 = wave_sum_dpp(fmaf(c0, c0, c1 * c1));
        const float inv2 = 1.0f / fmaxf(sqrtf(ss2), 1e-12f);
        const float b0 = c0 * inv2;
        const float b1 = c1 * inv2;

        const float l1 = wave_sum_dpp(fabsf(b0) + fabsf(b1));
        const float invl = 1.0f / fmaxf(l1, 1e-12f);
        const float o0 = sqrtf(fmaf(b0, invl, 1e-10f));
        const float o1 = sqrtf(fmaf(b1, invl, 1e-10f));

        // reference layout: desc[ang*16 + i*4 + j]
        out[(size_t)b * DESC + (a0i * 16 + ii0 * 4 + jj0)] = o0;
        out[(size_t)b * DESC + (a1i * 16 + ii1 * 4 + jj1)] = o1;
    }
}

extern "C" void kernel_launch(void* const* d_in, const int* in_sizes, int n_in,
                              void* d_out, int out_size, void* d_ws, size_t ws_size,
                              hipStream_t stream) {
    const float* input = (const float*)d_in[0];
    const float* gk    = (const float*)d_in[1];
    float* out         = (float*)d_out;

    const int B = in_sizes[0] / PSIZE;
    if (B <= 0) return;
    sift_desc_kernel<<<dim3(B), dim3(512), 0, stream>>>(input, gk, out);
}

// Round 19
// 38.240 us; speedup vs baseline: 1.1133x; 1.1133x over previous
//
#include <hip/hip_runtime.h>
#include <hip/hip_fp16.h>
#include <math.h>

#define PATCH 41
#define PSIZE (PATCH * PATCH)   // 1681
#define NUM_ANG 8
#define KS 16
#define STRIDE 10
#define PAD 4
#define DESC 128
#define CLIPVAL 0.2f

#define NQ4 (PATCH * 10)         // 410 uniform quads (x = 0..39)
#define CST 33                   // colsum row stride (floats, ODD -> bank spread)
#define ROWH (PATCH * 8)         // s_bins row stride in halves

struct F4 { float x, y, z, w; };

// ---- DPP-based wave64 sum (VALU pipe only, no LDS, no barriers) ----
template <int CTRL>
__device__ __forceinline__ float dpp_add(float v) {
    const int s = __builtin_amdgcn_update_dpp(
        0, __builtin_bit_cast(int, v), CTRL, 0xF, 0xF, true);
    return v + __builtin_bit_cast(float, s);
}
__device__ __forceinline__ float wave_sum_dpp(float v) {
    v = dpp_add<0x111>(v);   // row_shr:1
    v = dpp_add<0x112>(v);   // row_shr:2
    v = dpp_add<0x114>(v);   // row_shr:4
    v = dpp_add<0x118>(v);   // row_shr:8
    v = dpp_add<0x142>(v);   // row_bcast:15
    v = dpp_add<0x143>(v);   // row_bcast:31 -> lane 63 = total
    return __builtin_bit_cast(float,
        __builtin_amdgcn_readlane(__builtin_bit_cast(int, v), 63));
}

// per-pixel: UN-HALVED gradients -> orientation -> two b16 slot writes
__device__ __forceinline__ void bin_px(__half* sb, int pix, float gx2, float gy2, float gkv) {
    float g2 = fmaf(gx2, gx2, 4e-10f);
    g2 = fmaf(gy2, gy2, g2);
    const float mag = __builtin_amdgcn_sqrtf(g2) * (gkv * 512.0f);

    const float gxp = gx2 + 2e-10f;
    const float ax = fabsf(gxp), ay = fabsf(gy2);
    const float mx = fmaxf(ax, ay);
    const float mn = fminf(ax, ay);
    const float t  = mn * __builtin_amdgcn_rcpf(fmaxf(mx, 1e-20f));
    const float s  = t * t;
    float r = t * fmaf(s, fmaf(s, fmaf(s, fmaf(s, 0.02652810f, -0.10839420f),
                                       0.22936229f), -0.42055650f), 1.27306897f);
    r = (ay > ax)     ? 2.0f - r : r;
    r = (gxp < 0.0f)  ? 4.0f - r : r;
    r = (gy2 < 0.0f)  ? 8.0f - r : r;      // octant units in [0, 8]

    const float bf = floorf(r);
    const float f  = r - bf;
    const int b0 = ((int)bf) & (NUM_ANG - 1);
    const int b1 = (b0 + 1) & (NUM_ANG - 1);
    __half* slot = sb + pix * NUM_ANG;
    slot[b0] = __float2half((1.0f - f) * mag);
    slot[b1] = __float2half(f * mag);
}

// x-pool over x in [X0, X0+NX): all weights/guards compile-time
template <int X0, int NX>
__device__ __forceinline__ void xpool_half(const __half* sb, float* cs) {
    float acc[8];
    #pragma unroll
    for (int i = 0; i < 8; ++i) acc[i] = 0.0f;

    #pragma unroll
    for (int xi = 0; xi < NX; ++xi) {
        const int x = X0 + xi;
        const __half2 h = *(const __half2*)(sb + x * NUM_ANG);
        const float h0 = __half2float(h.x);
        const float h1 = __half2float(h.y);
        #pragma unroll
        for (int j = 0; j < 4; ++j) {
            const int dd = x - (j * STRIDE - PAD);
            if (dd >= 0 && dd < KS) {           // compile-time after unroll
                const float w = ((dd < 8 ? dd : 15 - dd) + 0.5f) * 0.125f;
                acc[j * 2]     = fmaf(w, h0, acc[j * 2]);
                acc[j * 2 + 1] = fmaf(w, h1, acc[j * 2 + 1]);
            }
        }
    }
    #pragma unroll
    for (int j = 0; j < 4; ++j) {
        cs[j * 8]     = acc[j * 2];
        cs[j * 8 + 1] = acc[j * 2 + 1];
    }
}

__global__ __launch_bounds__(512) void sift_desc_kernel(
    const float* __restrict__ input,
    const float* __restrict__ gk,
    float* __restrict__ out)
{
    __shared__ __align__(16) __half s_bins[PSIZE * NUM_ANG];  // 26896 B, [pix][a]
    __shared__ float s_ps[2 * PATCH * CST];                   // 10824 B, two x-halves

    const int tid = threadIdx.x;
    const int b   = blockIdx.x;
    const float* in_p = input + (size_t)b * PSIZE;

    const float w1r[KS] = {0.0625f, 0.1875f, 0.3125f, 0.4375f,
                           0.5625f, 0.6875f, 0.8125f, 0.9375f,
                           0.9375f, 0.8125f, 0.6875f, 0.5625f,
                           0.4375f, 0.3125f, 0.1875f, 0.0625f};

    // ---- phase 0: zero the bins (1681 x 16B) ----
    {
        float4* z = (float4*)s_bins;
        const float4 zero = make_float4(0.f, 0.f, 0.f, 0.f);
        for (int i = tid; i < PSIZE; i += 512) z[i] = zero;
    }
    __syncthreads();

    // ---- phase 1 (flat): one quad/thread; tail column on wave-7 threads ----
    if (tid < NQ4) {
        const int y  = tid / 10;
        const int xq = (tid - y * 10) * 4;
        const int ym = max(y - 1, 0), yp = min(y + 1, PATCH - 1);
        const float* cr = in_p + y  * PATCH;
        const float* ur = in_p + ym * PATCH;
        const float* dr = in_p + yp * PATCH;
        const float* gr = gk + y * PATCH;
        const int pix = y * PATCH + xq;

        const F4 c = *(const F4*)(cr + xq);
        const F4 u = *(const F4*)(ur + xq);
        const F4 d = *(const F4*)(dr + xq);
        const F4 g = *(const F4*)(gr + xq);
        const float L = cr[max(xq - 1, 0)];
        const float R = cr[xq + 4];

        bin_px(s_bins, pix,     (c.y - L),   (d.x - u.x), g.x);
        bin_px(s_bins, pix + 1, (c.z - c.x), (d.y - u.y), g.y);
        bin_px(s_bins, pix + 2, (c.w - c.y), (d.z - u.z), g.z);
        bin_px(s_bins, pix + 3, (R  - c.z),  (d.w - u.w), g.w);
    } else if (tid >= 448 && tid < 448 + PATCH) {   // tail column x = 40
        const int y = tid - 448;
        const int ym = max(y - 1, 0), yp = min(y + 1, PATCH - 1);
        const float* cr = in_p + y * PATCH;
        bin_px(s_bins, y * PATCH + 40,
               (cr[40] - cr[39]),
               (in_p[yp * PATCH + 40] - in_p[ym * PATCH + 40]),
               gk[y * PATCH + 40]);
    }
    __syncthreads();

    // ---- phase 2a: (angle-pair k, row y) x two x-halves on separate waves ----
    // waves 0-2: x in [0,21); waves 4-6: x in [21,41). h is wave-uniform.
    if (tid < 164) {
        const int k = tid & 3;
        const int y = tid >> 2;
        xpool_half<0, 21>(s_bins + y * ROWH + k * 2,
                          s_ps + y * CST + k * 2);
    } else if (tid >= 256 && tid < 256 + 164) {
        const int t2 = tid - 256;
        const int k = t2 & 3;
        const int y = t2 >> 2;
        xpool_half<21, 20>(s_bins + y * ROWH + k * 2,
                           s_ps + (PATCH + y) * CST + k * 2);
    }
    __syncthreads();

    // ---- phases 2b + norm: single wave, DPP reductions ----
    if (tid < 64) {
        const int lane = tid;
        float v0 = 0.0f, v1 = 0.0f;
        int a0i = 0, jj0 = 0, ii0 = 0, a1i = 0, jj1 = 0, ii1 = 0;
        #pragma unroll
        for (int h = 0; h < 2; ++h) {
            const int item = lane + h * 64;
            const int a  = item & 7;
            const int jj = (item >> 3) & 3;
            const int ii = item >> 5;
            const int py0 = ii * STRIDE - PAD;
            float s = 0.0f;
            #pragma unroll
            for (int dy = 0; dy < KS; ++dy) {
                const int py  = py0 + dy;
                const int pyc = min(max(py, 0), PATCH - 1);
                const float wv = (py == pyc) ? w1r[dy] : 0.0f;
                const float cs = s_ps[pyc * CST + jj * 8 + a]
                               + s_ps[(PATCH + pyc) * CST + jj * 8 + a];
                s = fmaf(wv, cs, s);
            }
            if (h == 0) { v0 = s; a0i = a; jj0 = jj; ii0 = ii; }
            else        { v1 = s; a1i = a; jj1 = jj; ii1 = ii; }
        }

        const float ss1 = wave_sum_dpp(fmaf(v0, v0, v1 * v1));
        const float inv1 = 1.0f / fmaxf(sqrtf(ss1), 1e-12f);
        const float c0 = fminf(fmaxf(v0 * inv1, 0.0f), CLIPVAL);
        const float c1 = fminf(fmaxf(v1 * inv1, 0.0f), CLIPVAL);

        const float ss2 = wave_sum_dpp(fmaf(c0, c0, c1 * c1));
        const float inv2 = 1.0f / fmaxf(sqrtf(ss2), 1e-12f);
        const float b0 = c0 * inv2;
        const float b1 = c1 * inv2;

        const float l1 = wave_sum_dpp(fabsf(b0) + fabsf(b1));
        const float invl = 1.0f / fmaxf(l1, 1e-12f);
        const float o0 = sqrtf(fmaf(b0, invl, 1e-10f));
        const float o1 = sqrtf(fmaf(b1, invl, 1e-10f));

        // reference layout: desc[ang*16 + i*4 + j]
        out[(size_t)b * DESC + (a0i * 16 + ii0 * 4 + jj0)] = o0;
        out[(size_t)b * DESC + (a1i * 16 + ii1 * 4 + jj1)] = o1;
    }
}

extern "C" void kernel_launch(void* const* d_in, const int* in_sizes, int n_in,
                              void* d_out, int out_size, void* d_ws, size_t ws_size,
                              hipStream_t stream) {
    const float* input = (const float*)d_in[0];
    const float* gk    = (const float*)d_in[1];
    float* out         = (float*)d_out;

    const int B = in_sizes[0] / PSIZE;
    if (B <= 0) return;
    sift_desc_kernel<<<dim3(B), dim3(512), 0, stream>>>(input, gk, out);
}